// Round 6
// baseline (25.523 us; speedup 1.0000x reference)
//
#include <hip/hip_runtime.h>

// RegionalCosineSimilarityLoss — B=8, T=2048, C=128; mapping sorted per batch, [0,64).
// mask(t,s) = (s>t) & (m_s <= m_t+3) & (m_t != 0)   [sortedness folds neighbor+padding]
// R6: single fused tile kernel — per-block normalize (f32->bf16) straight into
// swizzled LDS, parallel binary searches, MFMA 64x64 band tiles. Tiny k_final.

#define TT 2048
#define CC 128
#define TM 64
#define SLOTS 4

typedef unsigned short ushort_t;
typedef __attribute__((ext_vector_type(8))) short v8s;   // 8 bf16 (4 VGPRs)
typedef __attribute__((ext_vector_type(4))) float v4f;   // MFMA accumulator

__device__ __forceinline__ unsigned pack2bf(float a, float b) {  // RNE f32->bf16 pair
    unsigned ua = __float_as_uint(a), ub = __float_as_uint(b);
    ua = (ua + 0x7FFFu + ((ua >> 16) & 1u)) >> 16;
    ub = (ub + 0x7FFFu + ((ub >> 16) & 1u)) & 0xFFFF0000u;
    return ua | ub;
}

// ---------------- Kernel 1: fused normalize + MFMA band tiles ----------------
// Block 256 = 4 waves; wave (wr,wc) owns a 32x32 quadrant of the 64x64 tile.
// LDS bf16 [64 rows][16 chunks of 16B], chunk-slot swizzle sl ^= (row&7).
// Staging: wave w normalizes rows [16w,16w+16): coalesced f32 load, shfl-reduce
// norm, scale, RNE-pack, swizzled ds_write_b32 (2-way banks = free).
__global__ void __launch_bounds__(256) k_tile(const float* __restrict__ x,
                                              const int* __restrict__ map,
                                              float* __restrict__ psum,
                                              int* __restrict__ pcnt) {
    __shared__ __align__(16) ushort_t As[TM * CC];   // 16 KB
    __shared__ __align__(16) ushort_t Bs[TM * CC];   // 16 KB
    __shared__ int mt_s[TM], et_s[TM], ms_s[TM];
    __shared__ float wsum[4];

    const int tile = blockIdx.x;              // 0..255
    const int slot = blockIdx.y;              // 0..SLOTS-1
    const int tid  = threadIdx.x;
    const int lane = tid & 63;
    const int wave = tid >> 6;
    const int b    = tile >> 5;
    const int t0   = (tile & 31) * TM;
    const int* mb  = map + b * TT;
    const float* xg = x + (size_t)(b * TT) * CC;

    // 64 parallel binary searches (threads 0..63)
    if (tid < TM) {
        const int t = t0 + tid;
        const int m = mb[t];
        int e = t;                            // empty band when m==0
        if (m != 0) {
            const int key = m + 3;
            int lo = t + 1, hi = TT;
            while (lo < hi) { int mid = (lo + hi) >> 1; if (mb[mid] <= key) lo = mid + 1; else hi = mid; }
            e = lo - 1;
        }
        mt_s[tid] = m; et_s[tid] = e;
    }
    __syncthreads();

    int e = et_s[lane];
    #pragma unroll
    for (int off = 32; off; off >>= 1) e = max(e, __shfl_xor(e, off));
    const int emax = e;

    // per-tile masked count (slot 0, wave 0): sum over rows of band length
    if (slot == 0 && wave == 0) {
        int c = et_s[lane] - (t0 + lane);
        #pragma unroll
        for (int off = 32; off; off >>= 1) c += __shfl_xor(c, off);
        if (lane == 0) pcnt[tile] = c;
    }

    int s_base = t0 + slot * TM;
    if (s_base > emax) {                      // inactive slot: cheap exit
        if (tid == 0) psum[tile * SLOTS + slot] = 0.0f;
        return;
    }

    // ---- stage A: normalize rows t0..t0+63 into swizzled bf16 LDS ----
    #pragma unroll 4
    for (int i = 0; i < 16; ++i) {
        const int r = wave * 16 + i;
        float2 v = ((const float2*)(xg + (size_t)(t0 + r) * CC))[lane];
        float ss = v.x * v.x + v.y * v.y;
        #pragma unroll
        for (int off = 32; off; off >>= 1) ss += __shfl_xor(ss, off);
        const float rn = 1.0f / fmaxf(sqrtf(ss), 1e-8f);
        ((unsigned*)&As[(r * 16 + ((lane >> 2) ^ (r & 7))) * 8])[lane & 3] =
            pack2bf(v.x * rn, v.y * rn);
    }

    const int wr = wave >> 1, wc = wave & 1;
    const int r16 = lane & 15, kgrp = lane >> 4;
    const int rowA0 = wr * 32 + r16, rowA1 = rowA0 + 16;
    const int rowB0 = wc * 32 + r16, rowB1 = rowB0 + 16;

    float lsum = 0.0f;

    for (; s_base <= emax; s_base += SLOTS * TM) {
        // ---- stage B chunk: normalize rows s_base..s_base+63 ----
        #pragma unroll 4
        for (int i = 0; i < 16; ++i) {
            const int r = wave * 16 + i;
            float2 v = ((const float2*)(xg + (size_t)(s_base + r) * CC))[lane];
            float ss = v.x * v.x + v.y * v.y;
            #pragma unroll
            for (int off = 32; off; off >>= 1) ss += __shfl_xor(ss, off);
            const float rn = 1.0f / fmaxf(sqrtf(ss), 1e-8f);
            ((unsigned*)&Bs[(r * 16 + ((lane >> 2) ^ (r & 7))) * 8])[lane & 3] =
                pack2bf(v.x * rn, v.y * rn);
        }
        if (tid < TM) ms_s[tid] = mb[s_base + tid];
        __syncthreads();

        v4f acc00 = {0,0,0,0}, acc01 = {0,0,0,0}, acc10 = {0,0,0,0}, acc11 = {0,0,0,0};
        #pragma unroll
        for (int kk = 0; kk < 4; ++kk) {
            const int sl = kk * 4 + kgrp;
            v8s a0 = *(const v8s*)&As[(rowA0 * 16 + (sl ^ (rowA0 & 7))) * 8];
            v8s a1 = *(const v8s*)&As[(rowA1 * 16 + (sl ^ (rowA1 & 7))) * 8];
            v8s b0 = *(const v8s*)&Bs[(rowB0 * 16 + (sl ^ (rowB0 & 7))) * 8];
            v8s b1 = *(const v8s*)&Bs[(rowB1 * 16 + (sl ^ (rowB1 & 7))) * 8];
            acc00 = __builtin_amdgcn_mfma_f32_16x16x32_bf16(a0, b0, acc00, 0, 0, 0);
            acc01 = __builtin_amdgcn_mfma_f32_16x16x32_bf16(a0, b1, acc01, 0, 0, 0);
            acc10 = __builtin_amdgcn_mfma_f32_16x16x32_bf16(a1, b0, acc10, 0, 0, 0);
            acc11 = __builtin_amdgcn_mfma_f32_16x16x32_bf16(a1, b1, acc11, 0, 0, 0);
        }

        // ---- masked epilogue: C row=(lane>>4)*4+reg (t), col=lane&15 (s) ----
        #pragma unroll
        for (int fi = 0; fi < 2; ++fi) {
            #pragma unroll
            for (int fj = 0; fj < 2; ++fj) {
                const v4f a = fi == 0 ? (fj == 0 ? acc00 : acc01) : (fj == 0 ? acc10 : acc11);
                const int s_loc = wc * 32 + fj * 16 + r16;
                const int s     = s_base + s_loc;
                const int m_s   = ms_s[s_loc];
                #pragma unroll
                for (int r = 0; r < 4; ++r) {
                    const int t_loc = wr * 32 + fi * 16 + kgrp * 4 + r;
                    const int t     = t0 + t_loc;
                    const int m_t   = mt_s[t_loc];
                    if ((m_t != 0) & (s > t) & (s <= et_s[t_loc])) {
                        const float d = a[r] - (m_s == m_t ? 1.0f : 0.0f);
                        lsum += d * d;
                    }
                }
            }
        }
        __syncthreads();   // protect Bs/ms before restage (rare multi-pass)
    }

    #pragma unroll
    for (int off = 32; off; off >>= 1) lsum += __shfl_xor(lsum, off);
    if (lane == 0) wsum[wave] = lsum;
    __syncthreads();
    if (tid == 0) psum[tile * SLOTS + slot] = wsum[0] + wsum[1] + wsum[2] + wsum[3];
}

// ---------------- Kernel 2: final reduce (tiny reads) ----------------
__global__ void __launch_bounds__(256) k_final(const float* __restrict__ psum,
                                               const int* __restrict__ pcnt,
                                               float* __restrict__ out,
                                               int n_sum, int n_cnt) {
    __shared__ double ssum[256];
    __shared__ long long scnt[256];
    double s = 0.0; long long c = 0;
    for (int i = threadIdx.x; i < n_sum; i += 256) s += (double)psum[i];
    for (int i = threadIdx.x; i < n_cnt; i += 256) c += (long long)pcnt[i];
    ssum[threadIdx.x] = s; scnt[threadIdx.x] = c;
    __syncthreads();
    #pragma unroll
    for (int off = 128; off; off >>= 1) {
        if (threadIdx.x < off) {
            ssum[threadIdx.x] += ssum[threadIdx.x + off];
            scnt[threadIdx.x] += scnt[threadIdx.x + off];
        }
        __syncthreads();
    }
    if (threadIdx.x == 0) out[0] = (float)(ssum[0] / ((double)scnt[0] + 1e-6));
}

extern "C" void kernel_launch(void* const* d_in, const int* in_sizes, int n_in,
                              void* d_out, int out_size, void* d_ws, size_t ws_size,
                              hipStream_t stream) {
    (void)n_in; (void)out_size; (void)ws_size;
    const float* x   = (const float*)d_in[0];
    const int*   map = (const int*)d_in[1];
    float* out = (float*)d_out;

    const int n_rows  = in_sizes[1];            // B*T = 16384
    const int n_tiles = n_rows / TM;            // 256

    float* ps = (float*)d_ws;                                   // n_tiles*SLOTS floats
    int*   pc = (int*)((char*)ps + (size_t)n_tiles * SLOTS * 4);// n_tiles ints

    k_tile <<<dim3(n_tiles, SLOTS), 256, 0, stream>>>(x, map, ps, pc);
    k_final<<<1, 256, 0, stream>>>(ps, pc, out, n_tiles * SLOTS, n_tiles);
}